// Round 16
// baseline (562.423 us; speedup 1.0000x reference)
//
#include <hip/hip_runtime.h>
#include <hip/hip_cooperative_groups.h>

namespace cg = cooperative_groups;

#define BDIM 8
#define NPTS 4096
#define KNEI 20
#define BN (BDIM*NPTS)        // 32768
#define NKCNT (NPTS*KNEI)     // 81920
#define EPSI 1e-5f
#define SLOPE 0.01f

typedef _Float16 half_t;
typedef __attribute__((ext_vector_type(2))) _Float16 h2v;
typedef __attribute__((ext_vector_type(8))) _Float16 h8v;
typedef __attribute__((ext_vector_type(4))) float f32x4;

__device__ __forceinline__ h2v cvt2(float a, float b) {
    return __builtin_bit_cast(h2v, __builtin_amdgcn_cvt_pkrtz(a, b));
}
__device__ __forceinline__ unsigned long long pack4_f16(const f32x4& a) {
    unsigned p0 = __builtin_bit_cast(unsigned, cvt2(a[0], a[1]));
    unsigned p1 = __builtin_bit_cast(unsigned, cvt2(a[2], a[3]));
    return ((unsigned long long)p1 << 32) | p0;
}

// ============ MEGA: all 5 phases, 256 blocks x 512 threads (1 block/CU guaranteed) ============
// block bid owns points [bid*128, bid*128+128); batch b = bid>>5 (32 blocks/batch).
__global__ __launch_bounds__(512, 2) void mega(const float* __restrict__ x,
        const int* __restrict__ ind, const float* __restrict__ W1,
        const float* __restrict__ W2, const float* __restrict__ W3,
        half_t* __restrict__ u, half_t* __restrict__ v,
        half_t* __restrict__ Wh2, half_t* __restrict__ Wh3,
        float* __restrict__ s1, float* __restrict__ s2,
        float* __restrict__ s3, float* __restrict__ out) {
    cg::grid_group grid = cg::this_grid();
    __shared__ __align__(16) unsigned char wlds[16384];   // W2 swz [0:8K), W3 swz [8K:16K)
    __shared__ __align__(16) unsigned char scr[32768];    // 8 waves x 2x2KB dbuf
    __shared__ float sacc[128];
    int tid = threadIdx.x;
    int lane = tid & 63, w = tid >> 6;                    // w in [0,8)
    int l15 = lane & 15, q = lane >> 4;
    int rw7 = l15 & 7;
    int bid = blockIdx.x;
    int b = bid >> 5;                                     // 32 blocks per batch
    const float inv = 1.0f / (float)NKCNT;

    // ---------------- Phase 0: u/v via MFMA (all 8 waves, 128 rows) ----------------
    {
        int row = bid * 128 + w * 16 + l15;
        h8v bx[2];
#pragma unroll
        for (int kc = 0; kc < 2; ++kc) {
            const float* xp = x + (size_t)row * 64 + kc * 32 + q * 8;
            f32x4 x0 = *(const f32x4*)xp;
            f32x4 x1 = *(const f32x4*)(xp + 4);
            h8v t;
#pragma unroll
            for (int j = 0; j < 4; ++j) { t[j] = (half_t)x0[j]; t[4 + j] = (half_t)x1[j]; }
            bx[kc] = t;
        }
        h8v wa[4][2], wd[4][2];
#pragma unroll
        for (int mt = 0; mt < 4; ++mt)
#pragma unroll
            for (int kc = 0; kc < 2; ++kc) {
                const float* wp = W1 + (mt * 16 + l15) * 128 + kc * 32 + q * 8;
                f32x4 a0 = *(const f32x4*)wp;
                f32x4 a1 = *(const f32x4*)(wp + 4);
                f32x4 b0 = *(const f32x4*)(wp + 64);
                f32x4 b1 = *(const f32x4*)(wp + 68);
                h8v ta, td;
#pragma unroll
                for (int j = 0; j < 4; ++j) {
                    ta[j] = (half_t)a0[j]; ta[4 + j] = (half_t)a1[j];
                    td[j] = (half_t)(b0[j] - a0[j]); td[4 + j] = (half_t)(b1[j] - a1[j]);
                }
                wa[mt][kc] = ta; wd[mt][kc] = td;
            }
#pragma unroll
        for (int mt = 0; mt < 4; ++mt) {
            f32x4 au = {0.f, 0.f, 0.f, 0.f}, av = {0.f, 0.f, 0.f, 0.f};
            au = __builtin_amdgcn_mfma_f32_16x16x32_f16(wa[mt][0], bx[0], au, 0, 0, 0);
            au = __builtin_amdgcn_mfma_f32_16x16x32_f16(wa[mt][1], bx[1], au, 0, 0, 0);
            av = __builtin_amdgcn_mfma_f32_16x16x32_f16(wd[mt][0], bx[0], av, 0, 0, 0);
            av = __builtin_amdgcn_mfma_f32_16x16x32_f16(wd[mt][1], bx[1], av, 0, 0, 0);
            *(unsigned long long*)(u + (size_t)row * 64 + mt * 16 + q * 4) = pack4_f16(au);
            *(unsigned long long*)(v + (size_t)row * 64 + mt * 16 + q * 4) = pack4_f16(av);
        }
        if (bid == 0) {
            for (int i = tid; i < 4096; i += 512) {
                Wh2[i] = (half_t)W2[i];
                Wh3[i] = (half_t)W3[i];
            }
        }
    }
    __threadfence();
    grid.sync();
    __threadfence();

    // ---------------- Phase 1: stats1 of h1 = u[ind]+v ----------------
    {
        if (tid < 128) sacc[tid] = 0.f;
        int rh = (lane >> 3) & 1, c8 = lane & 7;
        float s[8] = {}, qa[8] = {};
#pragma unroll
        for (int sg = 0; sg < 4; ++sg) {
            int p = bid * 128 + sg * 32 + w * 4 + (lane >> 4);
            const int* ip = ind + (size_t)p * 20;
            int idx[10];
#pragma unroll
            for (int r = 0; r < 10; ++r) idx[r] = ip[r * 2 + rh];
            h8v vv = *(const h8v*)(v + (size_t)p * 64 + c8 * 8);
            h8v g[10];
#pragma unroll
            for (int r = 0; r < 10; ++r)
                g[r] = *(const h8v*)(u + (size_t)idx[r] * 64 + c8 * 8);
#pragma unroll
            for (int r = 0; r < 10; ++r) {
                h8v h = g[r] + vv;
#pragma unroll
                for (int j = 0; j < 8; ++j) {
                    float f = (float)h[j];
                    s[j] += f; qa[j] = fmaf(f, f, qa[j]);
                }
            }
        }
#pragma unroll
        for (int m = 8; m <= 32; m <<= 1)
#pragma unroll
            for (int j = 0; j < 8; ++j) {
                s[j] += __shfl_xor(s[j], m, 64);
                qa[j] += __shfl_xor(qa[j], m, 64);
            }
        __syncthreads();
        if ((lane & 56) == 0) {
#pragma unroll
            for (int j = 0; j < 8; ++j) {
                atomicAdd(&sacc[c8 * 8 + j], s[j]);
                atomicAdd(&sacc[64 + c8 * 8 + j], qa[j]);
            }
        }
        __syncthreads();
        if (tid < 128)
            atomicAdd(&s1[(tid >> 6) * 512 + b * 64 + (tid & 63)], sacc[tid]);
    }
    __threadfence();
    grid.sync();
    __threadfence();

    // ---------------- Phase 2: gather -> norm1+lrelu -> GEMM2 -> stats2 ----------------
    {
        if (tid < 128) sacc[tid] = 0.f;
        h8v aw[4][2];
#pragma unroll
        for (int mt = 0; mt < 4; ++mt)
#pragma unroll
            for (int kc = 0; kc < 2; ++kc)
                aw[mt][kc] = *(const h8v*)(Wh2 + (mt * 16 + l15) * 64 + kc * 32 + q * 8);
        h8v r1v[2], m1b[2];
#pragma unroll
        for (int kc = 0; kc < 2; ++kc) {
            const float* sp = s1 + b * 64 + kc * 32 + q * 8;
            f32x4 sm0 = *(const f32x4*)sp;
            f32x4 sm1 = *(const f32x4*)(sp + 4);
            f32x4 sq0 = *(const f32x4*)(sp + 512);
            f32x4 sq1 = *(const f32x4*)(sp + 516);
#pragma unroll
            for (int j = 0; j < 8; ++j) {
                float mm = (j < 4 ? sm0[j & 3] : sm1[j & 3]) * inv;
                float va = (j < 4 ? sq0[j & 3] : sq1[j & 3]) * inv - mm * mm;
                float rs = rsqrtf(va + EPSI);
                r1v[kc][j] = (half_t)rs;
                m1b[kc][j] = (half_t)(-mm * rs);
            }
        }
        float ss[4][4] = {}, sq[4][4] = {};
#pragma unroll
        for (int sg = 0; sg < 4; ++sg) {
            int base = bid * 128 + sg * 32;
            int base20 = base * 20;
            int idxs[5];
#pragma unroll
            for (int nt = 0; nt < 5; ++nt)
                idxs[nt] = ind[base20 + w * 80 + l15 * 5 + nt];
            h8v ug[5][2];
#pragma unroll
            for (int nt = 0; nt < 5; ++nt) {
                const half_t* up = u + (size_t)idxs[nt] * 64 + q * 8;
                ug[nt][0] = *(const h8v*)up;
                ug[nt][1] = *(const h8v*)(up + 32);
            }
            int gp = base + w * 4 + (l15 >> 2);
            h8v vfr0 = *(const h8v*)(v + (size_t)gp * 64 + q * 8);
            h8v vfr1 = *(const h8v*)(v + (size_t)gp * 64 + 32 + q * 8);
            h8v vn[2];
            vn[0] = vfr0 * r1v[0] + m1b[0];
            vn[1] = vfr1 * r1v[1] + m1b[1];
#pragma unroll
            for (int nt = 0; nt < 5; ++nt) {
                h8v t0 = ug[nt][0] * r1v[0] + vn[0];
                h8v t1 = ug[nt][1] * r1v[1] + vn[1];
                h8v b0 = __builtin_elementwise_max(t0, t0 * (half_t)SLOPE);
                h8v b1 = __builtin_elementwise_max(t1, t1 * (half_t)SLOPE);
#pragma unroll
                for (int mt = 0; mt < 4; ++mt) {
                    f32x4 a = {0.f, 0.f, 0.f, 0.f};
                    a = __builtin_amdgcn_mfma_f32_16x16x32_f16(aw[mt][0], b0, a, 0, 0, 0);
                    a = __builtin_amdgcn_mfma_f32_16x16x32_f16(aw[mt][1], b1, a, 0, 0, 0);
#pragma unroll
                    for (int j = 0; j < 4; ++j) {
                        ss[mt][j] += a[j];
                        sq[mt][j] = fmaf(a[j], a[j], sq[mt][j]);
                    }
                }
            }
        }
#pragma unroll
        for (int m = 1; m < 16; m <<= 1)
#pragma unroll
            for (int mt = 0; mt < 4; ++mt)
#pragma unroll
                for (int j = 0; j < 4; ++j) {
                    ss[mt][j] += __shfl_xor(ss[mt][j], m, 64);
                    sq[mt][j] += __shfl_xor(sq[mt][j], m, 64);
                }
        __syncthreads();
        if (l15 == 0) {
#pragma unroll
            for (int mt = 0; mt < 4; ++mt)
#pragma unroll
                for (int j = 0; j < 4; ++j) {
                    atomicAdd(&sacc[mt * 16 + q * 4 + j], ss[mt][j]);
                    atomicAdd(&sacc[64 + mt * 16 + q * 4 + j], sq[mt][j]);
                }
        }
        __syncthreads();
        if (tid < 128)
            atomicAdd(&s2[(tid >> 6) * 512 + b * 64 + (tid & 63)], sacc[tid]);
    }
    __threadfence();
    grid.sync();
    __threadfence();

    // ---------------- Phase 3: pipelined GEMM2->scr(dbuf)->GEMM3 -> max + stats3 ----------------
    {
        if (tid < 128) sacc[tid] = 0.f;
        {
            int rw = tid >> 3, ch = tid & 7;
            *(h8v*)(wlds + rw * 128 + ((ch ^ (rw & 7)) << 4)) =
                *(const h8v*)(Wh2 + rw * 64 + ch * 8);
            *(h8v*)(wlds + 8192 + rw * 128 + ((ch ^ (rw & 7)) << 4)) =
                *(const h8v*)(Wh3 + rw * 64 + ch * 8);
        }
        h8v r1v[2], m1b[2], r2v[2], m2v[2];
#pragma unroll
        for (int kc = 0; kc < 2; ++kc) {
            const float* sp1 = s1 + b * 64 + kc * 32 + q * 8;
            const float* sp2 = s2 + b * 64 + kc * 32 + q * 8;
            f32x4 a0 = *(const f32x4*)sp1;
            f32x4 a1 = *(const f32x4*)(sp1 + 4);
            f32x4 b0 = *(const f32x4*)(sp1 + 512);
            f32x4 b1 = *(const f32x4*)(sp1 + 516);
            f32x4 c0 = *(const f32x4*)sp2;
            f32x4 c1 = *(const f32x4*)(sp2 + 4);
            f32x4 d0 = *(const f32x4*)(sp2 + 512);
            f32x4 d1 = *(const f32x4*)(sp2 + 516);
#pragma unroll
            for (int j = 0; j < 8; ++j) {
                float mm = (j < 4 ? a0[j & 3] : a1[j & 3]) * inv;
                float va = (j < 4 ? b0[j & 3] : b1[j & 3]) * inv - mm * mm;
                float rs = rsqrtf(va + EPSI);
                r1v[kc][j] = (half_t)rs;
                m1b[kc][j] = (half_t)(-mm * rs);
                float mm2 = (j < 4 ? c0[j & 3] : c1[j & 3]) * inv;
                float va2 = (j < 4 ? d0[j & 3] : d1[j & 3]) * inv - mm2 * mm2;
                float rs2 = rsqrtf(va2 + EPSI);
                r2v[kc][j] = (half_t)rs2;
                m2v[kc][j] = (half_t)(-mm2 * rs2);
            }
        }
        unsigned char* scrw0 = scr + w * 4096;
        int t3 = w >> 2, w4 = w & 3;     // 2 teams of 4 waves
        __syncthreads();   // wlds staged; sacc zeroed
        float ss[4][4] = {}, sq[4][4] = {};
#pragma unroll
        for (int sg = 0; sg < 4; ++sg) {
            int base_t = bid * 128 + sg * 32 + t3 * 16;
            int base20 = base_t * 20;
            int idxs[5];
#pragma unroll
            for (int nt = 0; nt < 5; ++nt)
                idxs[nt] = ind[base20 + w4 * 80 + l15 * 5 + nt];
            const half_t* up0 = u + (size_t)idxs[0] * 64 + q * 8;
            h8v cu0 = *(const h8v*)up0;
            h8v cu1 = *(const h8v*)(up0 + 32);
            int gp = base_t + w4 * 4 + (l15 >> 2);
            h8v vfr0 = *(const h8v*)(v + (size_t)gp * 64 + q * 8);
            h8v vfr1 = *(const h8v*)(v + (size_t)gp * 64 + 32 + q * 8);
            h8v vn[2];
            vn[0] = vfr0 * r1v[0] + m1b[0];
            vn[1] = vfr1 * r1v[1] + m1b[1];
            h2v pm[4][2];
#pragma unroll
            for (int mt = 0; mt < 4; ++mt)
#pragma unroll
                for (int r = 0; r < 2; ++r)
                    pm[mt][r] = (h2v){(half_t)-65504.f, (half_t)-65504.f};
#pragma unroll
            for (int nt = 0; nt < 6; ++nt) {
                if (nt < 5) {
                    h8v nx0, nx1;
                    if (nt < 4) {
                        const half_t* upn = u + (size_t)idxs[nt + 1] * 64 + q * 8;
                        nx0 = *(const h8v*)upn;
                        nx1 = *(const h8v*)(upn + 32);
                    }
                    unsigned char* scrw = scrw0 + (nt & 1) * 2048;
                    h8v t0 = cu0 * r1v[0] + vn[0];
                    h8v t1 = cu1 * r1v[1] + vn[1];
                    h8v b0 = __builtin_elementwise_max(t0, t0 * (half_t)SLOPE);
                    h8v b1 = __builtin_elementwise_max(t1, t1 * (half_t)SLOPE);
#pragma unroll
                    for (int mt = 0; mt < 4; ++mt) {
                        h8v w0 = *(const h8v*)(wlds + (mt * 16 + l15) * 128 + ((q ^ rw7) << 4));
                        h8v w1 = *(const h8v*)(wlds + (mt * 16 + l15) * 128 + (((4 + q) ^ rw7) << 4));
                        f32x4 a = {0.f, 0.f, 0.f, 0.f};
                        a = __builtin_amdgcn_mfma_f32_16x16x32_f16(w0, b0, a, 0, 0, 0);
                        a = __builtin_amdgcn_mfma_f32_16x16x32_f16(w1, b1, a, 0, 0, 0);
                        *(unsigned long long*)(scrw + l15 * 128 +
                            (((mt * 2 + (q >> 1)) ^ rw7) << 4) + (q & 1) * 8) = pack4_f16(a);
                    }
                    if (nt < 4) { cu0 = nx0; cu1 = nx1; }
                }
                if (nt > 0) {
                    int m = nt - 1;
                    unsigned char* scrr = scrw0 + (m & 1) * 2048;
                    h8v hr0 = *(const h8v*)(scrr + l15 * 128 + ((q ^ rw7) << 4));
                    h8v hr1 = *(const h8v*)(scrr + l15 * 128 + (((4 + q) ^ rw7) << 4));
                    h8v t0 = hr0 * r2v[0] + m2v[0];
                    h8v t1 = hr1 * r2v[1] + m2v[1];
                    h8v b0 = __builtin_elementwise_max(t0, t0 * (half_t)SLOPE);
                    h8v b1 = __builtin_elementwise_max(t1, t1 * (half_t)SLOPE);
#pragma unroll
                    for (int mt = 0; mt < 4; ++mt) {
                        h8v w0 = *(const h8v*)(wlds + 8192 + (mt * 16 + l15) * 128 + ((q ^ rw7) << 4));
                        h8v w1 = *(const h8v*)(wlds + 8192 + (mt * 16 + l15) * 128 + (((4 + q) ^ rw7) << 4));
                        f32x4 a = {0.f, 0.f, 0.f, 0.f};
                        a = __builtin_amdgcn_mfma_f32_16x16x32_f16(w0, b0, a, 0, 0, 0);
                        a = __builtin_amdgcn_mfma_f32_16x16x32_f16(w1, b1, a, 0, 0, 0);
#pragma unroll
                        for (int j = 0; j < 4; ++j) {
                            ss[mt][j] += a[j];
                            sq[mt][j] = fmaf(a[j], a[j], sq[mt][j]);
                        }
                        h2v p0 = cvt2(a[0], a[1]);
                        h2v p1 = cvt2(a[2], a[3]);
                        pm[mt][0] = __builtin_elementwise_max(pm[mt][0], p0);
                        pm[mt][1] = __builtin_elementwise_max(pm[mt][1], p1);
                    }
                }
            }
#pragma unroll
            for (int m = 1; m <= 2; m <<= 1)
#pragma unroll
                for (int mt = 0; mt < 4; ++mt)
#pragma unroll
                    for (int r = 0; r < 2; ++r) {
                        int t = __shfl_xor(__builtin_bit_cast(int, pm[mt][r]), m, 64);
                        pm[mt][r] = __builtin_elementwise_max(pm[mt][r],
                                       __builtin_bit_cast(h2v, t));
                    }
            int ms = l15 & 3;
            h2v sa = ms == 0 ? pm[0][0] : ms == 1 ? pm[1][0] : ms == 2 ? pm[2][0] : pm[3][0];
            h2v sb = ms == 0 ? pm[0][1] : ms == 1 ? pm[1][1] : ms == 2 ? pm[2][1] : pm[3][1];
            f32x4 o = {(float)sa[0], (float)sa[1], (float)sb[0], (float)sb[1]};
            *(f32x4*)(out + (size_t)gp * 64 + ms * 16 + q * 4) = o;
        }
#pragma unroll
        for (int m = 1; m < 16; m <<= 1)
#pragma unroll
            for (int mt = 0; mt < 4; ++mt)
#pragma unroll
                for (int j = 0; j < 4; ++j) {
                    ss[mt][j] += __shfl_xor(ss[mt][j], m, 64);
                    sq[mt][j] += __shfl_xor(sq[mt][j], m, 64);
                }
        if (l15 == 0) {
#pragma unroll
            for (int mt = 0; mt < 4; ++mt)
#pragma unroll
                for (int j = 0; j < 4; ++j) {
                    atomicAdd(&sacc[mt * 16 + q * 4 + j], ss[mt][j]);
                    atomicAdd(&sacc[64 + mt * 16 + q * 4 + j], sq[mt][j]);
                }
        }
        __syncthreads();
        if (tid < 128)
            atomicAdd(&s3[(tid >> 6) * 512 + b * 64 + (tid & 63)], sacc[tid]);
    }
    __threadfence();
    grid.sync();
    __threadfence();

    // ---------------- Phase 4: out = lrelu((out - mean3) * rstd3), in place ----------------
    {
#pragma unroll
        for (int i = 0; i < 16; ++i) {
            int idx = bid * 8192 + i * 512 + tid;
            int c = idx & 63;
            int b4 = idx >> 18;
            float mm = s3[b4 * 64 + c] * inv;
            float vv = s3[512 + b4 * 64 + c] * inv - mm * mm;
            float r = rsqrtf(vv + EPSI);
            float val = (out[idx] - mm) * r;
            out[idx] = val >= 0.f ? val : SLOPE * val;
        }
    }
}

extern "C" void kernel_launch(void* const* d_in, const int* in_sizes, int n_in,
                              void* d_out, int out_size, void* d_ws, size_t ws_size,
                              hipStream_t stream) {
    const float* x   = (const float*)d_in[0];
    const int*   ind = (const int*)d_in[1];
    const float* W1  = (const float*)d_in[2];
    const float* W2  = (const float*)d_in[3];
    const float* W3  = (const float*)d_in[4];
    float* out = (float*)d_out;

    half_t* u   = (half_t*)d_ws;                       // [32768][64] f16
    half_t* v   = u + (size_t)BN * 64;                 // [32768][64] f16
    half_t* Wh2 = v + (size_t)BN * 64;                 // [64][64] f16
    half_t* Wh3 = Wh2 + 4096;                          // [64][64] f16
    float* stats = (float*)(Wh3 + 4096);
    float* s1 = stats;          // [2][512]
    float* s2 = stats + 1024;   // [2][512]
    float* s3 = stats + 2048;   // [2][512]

    (void)hipMemsetAsync(stats, 0, 3 * 1024 * sizeof(float), stream);
    void* args[] = {&x, &ind, &W1, &W2, &W3, &u, &v, &Wh2, &Wh3, &s1, &s2, &s3, &out};
    (void)hipLaunchCooperativeKernel((const void*)mega, dim3(256), dim3(512),
                                     args, 0, stream);
}

// Round 17
// 170.630 us; speedup vs baseline: 3.2961x; 3.2961x over previous
//
#include <hip/hip_runtime.h>

#define BDIM 8
#define NPTS 4096
#define KNEI 20
#define BN (BDIM*NPTS)        // 32768
#define NKCNT (NPTS*KNEI)     // 81920
#define EPSI 1e-5f
#define SLOPE 0.01f

typedef _Float16 half_t;
typedef __attribute__((ext_vector_type(2))) _Float16 h2v;
typedef __attribute__((ext_vector_type(4))) _Float16 h4v;
typedef __attribute__((ext_vector_type(8))) _Float16 h8v;
typedef __attribute__((ext_vector_type(4))) float f32x4;
typedef __attribute__((ext_vector_type(2))) float f32x2;

__device__ __forceinline__ h2v cvt2(float a, float b) {
    return __builtin_bit_cast(h2v, __builtin_amdgcn_cvt_pkrtz(a, b));
}
__device__ __forceinline__ unsigned long long pack4_f16(const f32x4& a) {
    unsigned p0 = __builtin_bit_cast(unsigned, cvt2(a[0], a[1]));
    unsigned p1 = __builtin_bit_cast(unsigned, cvt2(a[2], a[3]));
    return ((unsigned long long)p1 << 32) | p0;
}

// ---------------- K0: u = x*W1a^T, v = x*(W1b-W1a)^T via MFMA (f16) ----------------
__global__ __launch_bounds__(256) void k0_uv(const float* __restrict__ x,
        const float* __restrict__ W1, const float* __restrict__ W2,
        const float* __restrict__ W3, half_t* __restrict__ u,
        half_t* __restrict__ v, half_t* __restrict__ Wh2,
        half_t* __restrict__ Wh3) {
    int tid = threadIdx.x;
    if (blockIdx.x >= BN / 64) {
        const float* src = (blockIdx.x == BN / 64) ? W2 : W3;
        half_t* dst = (blockIdx.x == BN / 64) ? Wh2 : Wh3;
        for (int i = tid; i < 4096; i += 256) dst[i] = (half_t)src[i];
        return;
    }
    int lane = tid & 63, w = tid >> 6;
    int l15 = lane & 15, q = lane >> 4;
    int row = blockIdx.x * 64 + w * 16 + l15;
    h8v bx[2];
#pragma unroll
    for (int kc = 0; kc < 2; ++kc) {
        const float* xp = x + (size_t)row * 64 + kc * 32 + q * 8;
        f32x4 x0 = *(const f32x4*)xp;
        f32x4 x1 = *(const f32x4*)(xp + 4);
        h8v t;
#pragma unroll
        for (int j = 0; j < 4; ++j) { t[j] = (half_t)x0[j]; t[4 + j] = (half_t)x1[j]; }
        bx[kc] = t;
    }
    h8v wa[4][2], wd[4][2];
#pragma unroll
    for (int mt = 0; mt < 4; ++mt)
#pragma unroll
        for (int kc = 0; kc < 2; ++kc) {
            const float* wp = W1 + (mt * 16 + l15) * 128 + kc * 32 + q * 8;
            f32x4 a0 = *(const f32x4*)wp;
            f32x4 a1 = *(const f32x4*)(wp + 4);
            f32x4 b0 = *(const f32x4*)(wp + 64);
            f32x4 b1 = *(const f32x4*)(wp + 68);
            h8v ta, td;
#pragma unroll
            for (int j = 0; j < 4; ++j) {
                ta[j] = (half_t)a0[j]; ta[4 + j] = (half_t)a1[j];
                td[j] = (half_t)(b0[j] - a0[j]); td[4 + j] = (half_t)(b1[j] - a1[j]);
            }
            wa[mt][kc] = ta; wd[mt][kc] = td;
        }
#pragma unroll
    for (int mt = 0; mt < 4; ++mt) {
        f32x4 au = {0.f, 0.f, 0.f, 0.f}, av = {0.f, 0.f, 0.f, 0.f};
        au = __builtin_amdgcn_mfma_f32_16x16x32_f16(wa[mt][0], bx[0], au, 0, 0, 0);
        au = __builtin_amdgcn_mfma_f32_16x16x32_f16(wa[mt][1], bx[1], au, 0, 0, 0);
        av = __builtin_amdgcn_mfma_f32_16x16x32_f16(wd[mt][0], bx[0], av, 0, 0, 0);
        av = __builtin_amdgcn_mfma_f32_16x16x32_f16(wd[mt][1], bx[1], av, 0, 0, 0);
        *(unsigned long long*)(u + (size_t)row * 64 + mt * 16 + q * 4) = pack4_f16(au);
        *(unsigned long long*)(v + (size_t)row * 64 + mt * 16 + q * 4) = pack4_f16(av);
    }
}

// ---------------- K1: stats1, 512 threads / 32 points per block ----------------
__global__ __launch_bounds__(512) void k1_stats1(const half_t* __restrict__ u,
        const half_t* __restrict__ v, const int* __restrict__ ind,
        float* __restrict__ s1) {
    __shared__ float sacc[128];
    int tid = threadIdx.x;
    if (tid < 128) sacc[tid] = 0.f;
    int lane = tid & 63, w = tid >> 6;              // w in [0,8)
    int b = blockIdx.x >> 7;
    int n0 = (blockIdx.x & 127) << 5;
    int p = b * NPTS + n0 + w * 4 + (lane >> 4);
    int rh = (lane >> 3) & 1, c8 = lane & 7;
    const int* ip = ind + (size_t)p * 20;
    int idx[10];
#pragma unroll
    for (int r = 0; r < 10; ++r) idx[r] = ip[r * 2 + rh];
    h8v vv = *(const h8v*)(v + (size_t)p * 64 + c8 * 8);
    h8v g[10];
#pragma unroll
    for (int r = 0; r < 10; ++r)
        g[r] = *(const h8v*)(u + (size_t)idx[r] * 64 + c8 * 8);
    float s[8] = {}, qa[8] = {};
#pragma unroll
    for (int r = 0; r < 10; ++r) {
        h8v h = g[r] + vv;
#pragma unroll
        for (int j = 0; j < 8; ++j) {
            float f = (float)h[j];
            s[j] += f; qa[j] = fmaf(f, f, qa[j]);
        }
    }
#pragma unroll
    for (int m = 8; m <= 32; m <<= 1)
#pragma unroll
        for (int j = 0; j < 8; ++j) {
            s[j] += __shfl_xor(s[j], m, 64);
            qa[j] += __shfl_xor(qa[j], m, 64);
        }
    __syncthreads();
    if ((lane & 56) == 0) {
#pragma unroll
        for (int j = 0; j < 8; ++j) {
            atomicAdd(&sacc[c8 * 8 + j], s[j]);
            atomicAdd(&sacc[64 + c8 * 8 + j], qa[j]);
        }
    }
    __syncthreads();
    if (tid < 128)
        atomicAdd(&s1[(tid >> 6) * 512 + b * 64 + (tid & 63)], sacc[tid]);
}

// ------ K2: 512 threads / 32 points; full 5-row prefetch -> GEMM2 -> stats2 ------
__global__ __launch_bounds__(512, 4) void k2_stats2(const half_t* __restrict__ u,
        const half_t* __restrict__ v, const int* __restrict__ ind,
        const half_t* __restrict__ Wh2, const float* __restrict__ s1,
        float* __restrict__ s2) {
    __shared__ float sacc[128];
    int tid = threadIdx.x;
    if (tid < 128) sacc[tid] = 0.f;
    int lane = tid & 63, w = tid >> 6;              // w in [0,8)
    int l15 = lane & 15, q = lane >> 4;
    int b = blockIdx.x >> 7;
    int n0 = (blockIdx.x & 127) << 5;
    int base = b * NPTS + n0;
    int base20 = base * 20;
    int idxs[5];
#pragma unroll
    for (int nt = 0; nt < 5; ++nt)
        idxs[nt] = ind[base20 + w * 80 + l15 * 5 + nt];
    h8v ug[5][2];
#pragma unroll
    for (int nt = 0; nt < 5; ++nt) {
        const half_t* up = u + (size_t)idxs[nt] * 64 + q * 8;
        ug[nt][0] = *(const h8v*)up;
        ug[nt][1] = *(const h8v*)(up + 32);
    }
    int gp = base + w * 4 + (l15 >> 2);
    h8v vfr[2];
    vfr[0] = *(const h8v*)(v + (size_t)gp * 64 + q * 8);
    vfr[1] = *(const h8v*)(v + (size_t)gp * 64 + 32 + q * 8);
    h8v aw[4][2];
#pragma unroll
    for (int mt = 0; mt < 4; ++mt)
#pragma unroll
        for (int kc = 0; kc < 2; ++kc)
            aw[mt][kc] = *(const h8v*)(Wh2 + (mt * 16 + l15) * 64 + kc * 32 + q * 8);
    const float inv = 1.0f / (float)NKCNT;
    h8v r1v[2], vn[2];
#pragma unroll
    for (int kc = 0; kc < 2; ++kc)
#pragma unroll
        for (int j = 0; j < 8; ++j) {
            int c = kc * 32 + q * 8 + j;
            float mm = s1[b * 64 + c] * inv;
            float va = s1[512 + b * 64 + c] * inv - mm * mm;
            float rs = rsqrtf(va + EPSI);
            r1v[kc][j] = (half_t)rs;
            vn[kc][j] = (half_t)(((float)vfr[kc][j] - mm) * rs);
        }
    float ss[4][4] = {}, sq[4][4] = {};
#pragma unroll
    for (int nt = 0; nt < 5; ++nt) {
        h8v t0 = ug[nt][0] * r1v[0] + vn[0];
        h8v t1 = ug[nt][1] * r1v[1] + vn[1];
        h8v b0 = __builtin_elementwise_max(t0, t0 * (half_t)SLOPE);
        h8v b1 = __builtin_elementwise_max(t1, t1 * (half_t)SLOPE);
#pragma unroll
        for (int mt = 0; mt < 4; ++mt) {
            f32x4 a = {0.f, 0.f, 0.f, 0.f};
            a = __builtin_amdgcn_mfma_f32_16x16x32_f16(aw[mt][0], b0, a, 0, 0, 0);
            a = __builtin_amdgcn_mfma_f32_16x16x32_f16(aw[mt][1], b1, a, 0, 0, 0);
#pragma unroll
            for (int j = 0; j < 4; ++j) {
                ss[mt][j] += a[j];
                sq[mt][j] = fmaf(a[j], a[j], sq[mt][j]);
            }
        }
    }
#pragma unroll
    for (int m = 1; m < 16; m <<= 1)
#pragma unroll
        for (int mt = 0; mt < 4; ++mt)
#pragma unroll
            for (int j = 0; j < 4; ++j) {
                ss[mt][j] += __shfl_xor(ss[mt][j], m, 64);
                sq[mt][j] += __shfl_xor(sq[mt][j], m, 64);
            }
    __syncthreads();
    if (l15 == 0) {
#pragma unroll
        for (int mt = 0; mt < 4; ++mt)
#pragma unroll
            for (int j = 0; j < 4; ++j) {
                atomicAdd(&sacc[mt * 16 + q * 4 + j], ss[mt][j]);
                atomicAdd(&sacc[64 + mt * 16 + q * 4 + j], sq[mt][j]);
            }
    }
    __syncthreads();
    if (tid < 128)
        atomicAdd(&s2[(tid >> 6) * 512 + b * 64 + (tid & 63)], sacc[tid]);
}

// ------ K3: 512 threads / 32 points; R7 pipelined GEMM2->scr(dbuf)->GEMM3 ------
__global__ __launch_bounds__(512, 4) void k3_fused(const half_t* __restrict__ u,
        const half_t* __restrict__ v, const int* __restrict__ ind,
        const half_t* __restrict__ Wh2, const half_t* __restrict__ Wh3,
        const float* __restrict__ s1, const float* __restrict__ s2,
        float* __restrict__ s3, float* __restrict__ out) {
    __shared__ __align__(16) unsigned char wlds[16384];   // W2 swz [0:8K), W3 swz [8K:16K)
    __shared__ __align__(16) unsigned char scr[32768];    // 8 waves x 2x2KB dbuf
    __shared__ float sacc[128];
    int tid = threadIdx.x;
    if (tid < 128) sacc[tid] = 0.f;
    int lane = tid & 63, w = tid >> 6;              // w in [0,8)
    int l15 = lane & 15, q = lane >> 4;
    int rw7 = l15 & 7;
    int b = blockIdx.x >> 7;
    int n0 = (blockIdx.x & 127) << 5;
    int base = b * NPTS + n0;
    int base20 = base * 20;
    // stage W2/W3 into LDS with chunk^(row&7) swizzle
    for (int i = tid; i < 512; i += 512) {
        int rw = i >> 3, ch = i & 7;
        *(h8v*)(wlds + rw * 128 + ((ch ^ (rw & 7)) << 4)) =
            *(const h8v*)(Wh2 + rw * 64 + ch * 8);
        *(h8v*)(wlds + 8192 + rw * 128 + ((ch ^ (rw & 7)) << 4)) =
            *(const h8v*)(Wh3 + rw * 64 + ch * 8);
    }
    int idxs[5];
#pragma unroll
    for (int nt = 0; nt < 5; ++nt)
        idxs[nt] = ind[base20 + w * 80 + l15 * 5 + nt];
    const half_t* up0 = u + (size_t)idxs[0] * 64 + q * 8;
    h8v cu0 = *(const h8v*)up0;
    h8v cu1 = *(const h8v*)(up0 + 32);
    int gp = base + w * 4 + (l15 >> 2);
    h8v vfr[2];
#pragma unroll
    for (int kc = 0; kc < 2; ++kc)
        vfr[kc] = *(const h8v*)(v + (size_t)gp * 64 + kc * 32 + q * 8);
    const float inv = 1.0f / (float)NKCNT;
    h8v r1v[2], vn[2], r2v[2], m2v[2];
#pragma unroll
    for (int kc = 0; kc < 2; ++kc)
#pragma unroll
        for (int j = 0; j < 8; ++j) {
            int c = kc * 32 + q * 8 + j;
            float mm = s1[b * 64 + c] * inv;
            float va = s1[512 + b * 64 + c] * inv - mm * mm;
            float rs = rsqrtf(va + EPSI);
            r1v[kc][j] = (half_t)rs;
            vn[kc][j] = (half_t)(((float)vfr[kc][j] - mm) * rs);
            float mm2 = s2[b * 64 + c] * inv;
            float va2 = s2[512 + b * 64 + c] * inv - mm2 * mm2;
            float rs2 = rsqrtf(va2 + EPSI);
            r2v[kc][j] = (half_t)rs2;
            m2v[kc][j] = (half_t)(-mm2 * rs2);
        }
    unsigned char* scrw0 = scr + w * 4096;
    __syncthreads();   // wlds staged; sacc zeroed
    float ss[4][4] = {}, sq[4][4] = {};
    h2v pm[4][2];
#pragma unroll
    for (int mt = 0; mt < 4; ++mt)
#pragma unroll
        for (int r = 0; r < 2; ++r)
            pm[mt][r] = (h2v){(half_t)-65504.f, (half_t)-65504.f};
#pragma unroll
    for (int nt = 0; nt < 6; ++nt) {
        // ---- Stage A(nt): gather -> norm1+lrelu -> GEMM2 -> scr[nt&1] ----
        if (nt < 5) {
            h8v nx0, nx1;
            if (nt < 4) {
                const half_t* upn = u + (size_t)idxs[nt + 1] * 64 + q * 8;
                nx0 = *(const h8v*)upn;
                nx1 = *(const h8v*)(upn + 32);
            }
            unsigned char* scrw = scrw0 + (nt & 1) * 2048;
            h8v t0 = cu0 * r1v[0] + vn[0];
            h8v t1 = cu1 * r1v[1] + vn[1];
            h8v b0 = __builtin_elementwise_max(t0, t0 * (half_t)SLOPE);
            h8v b1 = __builtin_elementwise_max(t1, t1 * (half_t)SLOPE);
#pragma unroll
            for (int mt = 0; mt < 4; ++mt) {
                h8v w0 = *(const h8v*)(wlds + (mt * 16 + l15) * 128 + ((q ^ rw7) << 4));
                h8v w1 = *(const h8v*)(wlds + (mt * 16 + l15) * 128 + (((4 + q) ^ rw7) << 4));
                f32x4 a = {0.f, 0.f, 0.f, 0.f};
                a = __builtin_amdgcn_mfma_f32_16x16x32_f16(w0, b0, a, 0, 0, 0);
                a = __builtin_amdgcn_mfma_f32_16x16x32_f16(w1, b1, a, 0, 0, 0);
                *(unsigned long long*)(scrw + l15 * 128 +
                    (((mt * 2 + (q >> 1)) ^ rw7) << 4) + (q & 1) * 8) = pack4_f16(a);
            }
            if (nt < 4) { cu0 = nx0; cu1 = nx1; }
        }
        // ---- Stage B(nt-1): read scr[(nt-1)&1] -> norm2+lrelu -> GEMM3 -> stats+max ----
        if (nt > 0) {
            int m = nt - 1;
            unsigned char* scrr = scrw0 + (m & 1) * 2048;
            h8v hr0 = *(const h8v*)(scrr + l15 * 128 + ((q ^ rw7) << 4));
            h8v hr1 = *(const h8v*)(scrr + l15 * 128 + (((4 + q) ^ rw7) << 4));
            h8v t0 = hr0 * r2v[0] + m2v[0];
            h8v t1 = hr1 * r2v[1] + m2v[1];
            h8v b0 = __builtin_elementwise_max(t0, t0 * (half_t)SLOPE);
            h8v b1 = __builtin_elementwise_max(t1, t1 * (half_t)SLOPE);
#pragma unroll
            for (int mt = 0; mt < 4; ++mt) {
                h8v w0 = *(const h8v*)(wlds + 8192 + (mt * 16 + l15) * 128 + ((q ^ rw7) << 4));
                h8v w1 = *(const h8v*)(wlds + 8192 + (mt * 16 + l15) * 128 + (((4 + q) ^ rw7) << 4));
                f32x4 a = {0.f, 0.f, 0.f, 0.f};
                a = __builtin_amdgcn_mfma_f32_16x16x32_f16(w0, b0, a, 0, 0, 0);
                a = __builtin_amdgcn_mfma_f32_16x16x32_f16(w1, b1, a, 0, 0, 0);
#pragma unroll
                for (int j = 0; j < 4; ++j) {
                    ss[mt][j] += a[j];
                    sq[mt][j] = fmaf(a[j], a[j], sq[mt][j]);
                }
                h2v p0 = cvt2(a[0], a[1]);
                h2v p1 = cvt2(a[2], a[3]);
                pm[mt][0] = __builtin_elementwise_max(pm[mt][0], p0);
                pm[mt][1] = __builtin_elementwise_max(pm[mt][1], p1);
            }
        }
    }
    // max all-reduce over the 4-lane l15 group (rows of one point)
#pragma unroll
    for (int m = 1; m <= 2; m <<= 1)
#pragma unroll
        for (int mt = 0; mt < 4; ++mt)
#pragma unroll
            for (int r = 0; r < 2; ++r) {
                int t = __shfl_xor(__builtin_bit_cast(int, pm[mt][r]), m, 64);
                pm[mt][r] = __builtin_elementwise_max(pm[mt][r],
                               __builtin_bit_cast(h2v, t));
            }
    {
        int ms = l15 & 3;
        h2v sa = ms == 0 ? pm[0][0] : ms == 1 ? pm[1][0] : ms == 2 ? pm[2][0] : pm[3][0];
        h2v sb = ms == 0 ? pm[0][1] : ms == 1 ? pm[1][1] : ms == 2 ? pm[2][1] : pm[3][1];
        f32x4 o = {(float)sa[0], (float)sa[1], (float)sb[0], (float)sb[1]};
        *(f32x4*)(out + (size_t)gp * 64 + ms * 16 + q * 4) = o;
    }
#pragma unroll
    for (int m = 1; m < 16; m <<= 1)
#pragma unroll
        for (int mt = 0; mt < 4; ++mt)
#pragma unroll
            for (int j = 0; j < 4; ++j) {
                ss[mt][j] += __shfl_xor(ss[mt][j], m, 64);
                sq[mt][j] += __shfl_xor(sq[mt][j], m, 64);
            }
    if (l15 == 0) {
#pragma unroll
        for (int mt = 0; mt < 4; ++mt)
#pragma unroll
            for (int j = 0; j < 4; ++j) {
                atomicAdd(&sacc[mt * 16 + q * 4 + j], ss[mt][j]);
                atomicAdd(&sacc[64 + mt * 16 + q * 4 + j], sq[mt][j]);
            }
    }
    __syncthreads();
    if (tid < 128)
        atomicAdd(&s3[(tid >> 6) * 512 + b * 64 + (tid & 63)], sacc[tid]);
}

// ---------------- K4: out = lrelu((out - mean3) * rstd3), in place ----------------
__global__ __launch_bounds__(256) void k4_final(float* __restrict__ out,
        const float* __restrict__ s3) {
    int idx = blockIdx.x * 256 + threadIdx.x;
    int c = idx & 63;
    int b = idx >> 18;
    const float inv = 1.0f / (float)NKCNT;
    float mm = s3[b * 64 + c] * inv;
    float vv = s3[512 + b * 64 + c] * inv - mm * mm;
    float r = rsqrtf(vv + EPSI);
    float val = (out[idx] - mm) * r;
    out[idx] = val >= 0.f ? val : SLOPE * val;
}

extern "C" void kernel_launch(void* const* d_in, const int* in_sizes, int n_in,
                              void* d_out, int out_size, void* d_ws, size_t ws_size,
                              hipStream_t stream) {
    const float* x   = (const float*)d_in[0];
    const int*   ind = (const int*)d_in[1];
    const float* W1  = (const float*)d_in[2];
    const float* W2  = (const float*)d_in[3];
    const float* W3  = (const float*)d_in[4];
    float* out = (float*)d_out;

    half_t* u   = (half_t*)d_ws;                       // [32768][64] f16
    half_t* v   = u + (size_t)BN * 64;                 // [32768][64] f16
    half_t* Wh2 = v + (size_t)BN * 64;                 // [64][64] f16
    half_t* Wh3 = Wh2 + 4096;                          // [64][64] f16
    float* stats = (float*)(Wh3 + 4096);
    float* s1 = stats;          // [2][512]
    float* s2 = stats + 1024;   // [2][512]
    float* s3 = stats + 2048;   // [2][512]

    (void)hipMemsetAsync(stats, 0, 3 * 1024 * sizeof(float), stream);
    k0_uv<<<dim3(BN / 64 + 2), dim3(256), 0, stream>>>(x, W1, W2, W3, u, v, Wh2, Wh3);
    k1_stats1<<<dim3(BN / 32), dim3(512), 0, stream>>>(u, v, ind, s1);
    k2_stats2<<<dim3(BN / 32), dim3(512), 0, stream>>>(u, v, ind, Wh2, s1, s2);
    k3_fused<<<dim3(BN / 32), dim3(512), 0, stream>>>(u, v, ind, Wh2, Wh3, s1, s2, s3, out);
    k4_final<<<dim3(BN * 64 / 256), dim3(256), 0, stream>>>(out, s3);
}